// Round 7
// baseline (373.535 us; speedup 1.0000x reference)
//
#include <hip/hip_runtime.h>
#include <hip/hip_bf16.h>
#include <math.h>

#define B 1024
#define D 512
#define KC 100000
#define MARGIN 0.3f
#define EPSSM 0.1f
#define NPANEL 391   // ceil(KC/256)

typedef __attribute__((ext_vector_type(8))) short bf16x8;
typedef __attribute__((ext_vector_type(4))) float f32x4;

__device__ __forceinline__ unsigned cvtpk(float lo, float hi) {
    union { __hip_bfloat162 h2; unsigned u; } cv;
    cv.h2 = __float22bfloat162_rn(make_float2(lo, hi));
    return cv.u;
}

__device__ __forceinline__ void async16(const void* g, void* l) {
    __builtin_amdgcn_global_load_lds((const __attribute__((address_space(1))) unsigned int*)g,
                                     (__attribute__((address_space(3))) unsigned int*)l,
                                     16, 0, 0);
}

#define VMCNT(n) asm volatile("s_waitcnt vmcnt(" #n ")" ::: "memory")
#define FENCE    asm volatile("" ::: "memory")

// ---------------- init workspace ----------------
__global__ void init_ws(float* ws) {
    int i = blockIdx.x * blockDim.x + threadIdx.x;
    if (i < 2 * B) ws[i] = 0.f;   // sumexp[B], sumlogit[B]
}

// ---------------- pack x -> bf16 LDS-image tiles (BK=32 geometry) ----------------
// Region (rblk 0..7, kt 0..15) = 4096 ushorts (8KB) = 128 rows x 4 units x 8 bf16.
// Data unit (rloc, ku) stored at position rloc*4 + (ku ^ (rloc&3)).
__global__ __launch_bounds__(256) void pack_x(const float* __restrict__ x,
                                              unsigned short* __restrict__ xp) {
    int gid = blockIdx.x * 256 + threadIdx.x;   // 1024 rows * 64 units
    int row = gid >> 6;
    int unit = gid & 63;
    int kt = unit >> 2, ku = unit & 3;
    int rblk = row >> 7, rloc = row & 127;
    const float* src = x + (size_t)row * D + kt * 32 + ku * 8;
    f32x4 a = *(const f32x4*)src;
    f32x4 b2 = *(const f32x4*)(src + 4);
    unsigned pv[4] = { cvtpk(a[0], a[1]), cvtpk(a[2], a[3]), cvtpk(b2[0], b2[1]), cvtpk(b2[2], b2[3]) };
    size_t off = ((size_t)(rblk * 16 + kt) << 12) + (size_t)(rloc * 4 + (ku ^ (rloc & 3))) * 8;
    *(uint4*)(xp + off) = *(uint4*)pv;
}

// ---------------- pack W -> bf16 LDS-image tiles (BK=32 geometry) ----------------
// Region (panel 0..390, kt 0..15) = 8192 ushorts (16KB) = 256 rows x 4 units.
// Non-temporal W reads keep wp LLC-resident for the GEMM.
__global__ __launch_bounds__(256) void pack_w(const float* __restrict__ W,
                                              unsigned short* __restrict__ wp) {
    size_t gid = (size_t)blockIdx.x * 256 + threadIdx.x;   // 100096*64 units
    int c = (int)(gid >> 6);
    int unit = (int)(gid & 63);
    int kt = unit >> 2, ku = unit & 3;
    unsigned pv[4];
    if (c < KC) {
        const float* src = W + (size_t)c * D + kt * 32 + ku * 8;
        f32x4 a = __builtin_nontemporal_load((const f32x4*)src);
        f32x4 b2 = __builtin_nontemporal_load((const f32x4*)(src + 4));
        pv[0] = cvtpk(a[0], a[1]);  pv[1] = cvtpk(a[2], a[3]);
        pv[2] = cvtpk(b2[0], b2[1]); pv[3] = cvtpk(b2[2], b2[3]);
    } else {
        pv[0] = pv[1] = pv[2] = pv[3] = 0u;
    }
    int panel = c >> 8, prow = c & 255;
    size_t off = ((size_t)(panel * 16 + kt) << 13) + (size_t)(prow * 4 + (ku ^ (prow & 3))) * 8;
    *(uint4*)(wp + off) = *(uint4*)pv;
}

// ---------------- triplet: batch-hard per 8 rows (fp32, small) ----------------
__global__ __launch_bounds__(256) void triplet_kernel(const float* __restrict__ x,
                                                      const int* __restrict__ labels,
                                                      float* __restrict__ tw) {
    const int tid = threadIdx.x;
    const int row0 = blockIdx.x * 8;
    __shared__ float xs[8][D];
    __shared__ int labs[8];
    __shared__ float sqi[8];
    __shared__ float red_ap[8][4], red_an[8][4];

    for (int f = tid; f < 8 * (D / 4); f += 256) {
        int r = f / (D / 4);
        int p = f % (D / 4);
        *(float4*)&xs[r][p * 4] = *(const float4*)&x[(size_t)(row0 + r) * D + p * 4];
    }
    if (tid < 8) labs[tid] = labels[row0 + tid];
    __syncthreads();
    if (tid < 8) {
        float s = 0.f;
        for (int k = 0; k < D; ++k) s += xs[tid][k] * xs[tid][k];
        sqi[tid] = s;
    }
    __syncthreads();

    float ap[8], an[8];
#pragma unroll
    for (int r = 0; r < 8; ++r) { ap[r] = -INFINITY; an[r] = INFINITY; }

    for (int j = tid; j < B; j += 256) {
        int labj = labels[j];
        float dot[8];
        float sqj = 0.f;
#pragma unroll
        for (int r = 0; r < 8; ++r) dot[r] = 0.f;
        for (int kc = 0; kc < D; kc += 32) {
            float4 xj[8];
#pragma unroll
            for (int u = 0; u < 8; ++u) xj[u] = *(const float4*)&x[(size_t)j * D + kc + u * 4];
#pragma unroll
            for (int u = 0; u < 8; ++u)
                sqj += xj[u].x * xj[u].x + xj[u].y * xj[u].y + xj[u].z * xj[u].z + xj[u].w * xj[u].w;
#pragma unroll
            for (int r = 0; r < 8; ++r) {
                float d = 0.f;
#pragma unroll
                for (int u = 0; u < 8; ++u) {
                    const float4 a = *(const float4*)&xs[r][kc + u * 4];
                    d += a.x * xj[u].x + a.y * xj[u].y + a.z * xj[u].z + a.w * xj[u].w;
                }
                dot[r] += d;
            }
        }
#pragma unroll
        for (int r = 0; r < 8; ++r) {
            float d2 = sqi[r] + sqj - 2.f * dot[r];
            float dist = sqrtf(fmaxf(d2, 1e-12f));
            if (labj == labs[r]) ap[r] = fmaxf(ap[r], dist);
            else an[r] = fminf(an[r], dist);
        }
    }
#pragma unroll
    for (int r = 0; r < 8; ++r) {
        for (int o = 32; o >= 1; o >>= 1) {
            ap[r] = fmaxf(ap[r], __shfl_xor(ap[r], o));
            an[r] = fminf(an[r], __shfl_xor(an[r], o));
        }
    }
    int wid = tid >> 6;
    if ((tid & 63) == 0) {
#pragma unroll
        for (int r = 0; r < 8; ++r) { red_ap[r][wid] = ap[r]; red_an[r][wid] = an[r]; }
    }
    __syncthreads();
    if (tid < 8) {
        float a = -INFINITY, n = INFINITY;
#pragma unroll
        for (int w = 0; w < 4; ++w) { a = fmaxf(a, red_ap[tid][w]); n = fminf(n, red_an[tid][w]); }
        tw[row0 + tid] = fmaxf(a - n + MARGIN, 0.f);
    }
}

// ---------------- label logit: t[i] = x_i . W[label_i] + b[label_i] (exact fp32) ---
__global__ __launch_bounds__(256) void tlabel_kernel(const float* __restrict__ x,
                                                     const float* __restrict__ W,
                                                     const float* __restrict__ bias,
                                                     const int* __restrict__ labels,
                                                     float* __restrict__ t) {
    int wid = threadIdx.x >> 6, lane = threadIdx.x & 63;
    int row = blockIdx.x * 4 + wid;
    int lab = labels[row];
    const float* xr = x + (size_t)row * D;
    const float* wr = W + (size_t)lab * D;
    float dsum = 0.f;
#pragma unroll
    for (int u = 0; u < 2; ++u) {
        int k = (lane * 2 + u) * 4;
        float4 a = *(const float4*)&xr[k];
        float4 w = *(const float4*)&wr[k];
        dsum += a.x * w.x + a.y * w.y + a.z * w.z + a.w * w.w;
    }
    for (int o = 32; o >= 1; o >>= 1) dsum += __shfl_xor(dsum, o);
    if (lane == 0) t[row] = dsum + bias[lab];
}

// ============ persistent 128x256xBK32 bf16 MFMA GEMM, 2 blocks/CU ============
// 256 thr (4 waves, all N-split; wave tile 128x64). LDS = 2 buffers x 24KB = 48KB
// -> 2 independent blocks/CU for stall overlap. Each block loops ~6 (panel,row)
// tasks on its XCD (8 panels concurrent per XCD -> W L2-resident). Per K-tile:
// {STAGE next (6 gload_lds), vmcnt(6), barrier, 12 conflict-free ds_read_b128,
//  32 MFMA @setprio, barrier}. Swizzle baked into pack layout.
__global__ __launch_bounds__(256, 2) void ce_gemm_t(const unsigned short* __restrict__ xp,
                                                    const unsigned short* __restrict__ wp,
                                                    const float* __restrict__ bias,
                                                    float* __restrict__ sumexp,
                                                    float* __restrict__ sumlogit) {
    const int g = blockIdx.x;
    const int xcd = g & 7, slot = g >> 3;   // 64 slots per XCD

    extern __shared__ unsigned short lds[];   // 24576 ushorts = 48KB

    const int tid = threadIdx.x;
    const int lane = tid & 63;
    const int wn = tid >> 6;                  // wave -> N quarter
    const int q = lane >> 4, l15 = lane & 15;

    for (int t = slot; t < 392; t += 64) {
        const int c = (t >> 3) * 8 + xcd;     // panel
        if (c >= NPANEL) continue;
        const int r = t & 7;                  // row-block
        const int rowbase = r * 128;
        const int cbase = c * 256;

        f32x4 acc[8][4];
#pragma unroll
        for (int m = 0; m < 8; ++m)
#pragma unroll
            for (int n = 0; n < 4; ++n) acc[m][n] = (f32x4){0.f, 0.f, 0.f, 0.f};

#define STAGE(kt_) {                                                              \
        unsigned short* lA = lds + ((kt_) & 1) * 12288;                           \
        const unsigned short* ga = xp + ((size_t)(r * 16 + (kt_)) << 12);         \
        async16(ga + tid * 8, lA + tid * 8);                                      \
        async16(ga + 2048 + tid * 8, lA + 2048 + tid * 8);                        \
        unsigned short* lB = lA + 4096;                                           \
        const unsigned short* gb = wp + ((size_t)(c * 16 + (kt_)) << 13);         \
        async16(gb + tid * 8, lB + tid * 8);                                      \
        async16(gb + 2048 + tid * 8, lB + 2048 + tid * 8);                        \
        async16(gb + 4096 + tid * 8, lB + 4096 + tid * 8);                        \
        async16(gb + 6144 + tid * 8, lB + 6144 + tid * 8); }

        STAGE(0);
#pragma unroll
        for (int kt = 0; kt < 16; ++kt) {
            if (kt < 15) { STAGE(kt + 1); VMCNT(6); } else { VMCNT(0); }
            __builtin_amdgcn_s_barrier(); FENCE;

            const unsigned short* bufA = lds + (kt & 1) * 12288;
            const unsigned short* bufB = bufA + 4096;
            bf16x8 af[8], bfr[4];
#pragma unroll
            for (int m = 0; m < 8; ++m) {
                int rl = m * 16 + l15;
                af[m] = *(const bf16x8*)&bufA[(rl * 4 + (q ^ (rl & 3))) * 8];
            }
#pragma unroll
            for (int n = 0; n < 4; ++n) {
                int rl = wn * 64 + n * 16 + l15;
                bfr[n] = *(const bf16x8*)&bufB[(rl * 4 + (q ^ (rl & 3))) * 8];
            }
            __builtin_amdgcn_s_setprio(1);
#pragma unroll
            for (int m = 0; m < 8; ++m)
#pragma unroll
                for (int n = 0; n < 4; ++n)
                    acc[m][n] = __builtin_amdgcn_mfma_f32_16x16x32_bf16(af[m], bfr[n], acc[m][n], 0, 0, 0);
            __builtin_amdgcn_s_setprio(0);
            __builtin_amdgcn_s_barrier(); FENCE;
        }
#undef STAGE

        // ---- epilogue: per-row sum(exp(logit)) / sum(logit) ----
        __syncthreads();
        float* redE = (float*)lds;         // [128][4] f32 = 2KB
        float* redL = redE + 512;          // [128][4]

#pragma unroll
        for (int m = 0; m < 8; ++m) {
            float pe[4] = {0.f, 0.f, 0.f, 0.f}, pl[4] = {0.f, 0.f, 0.f, 0.f};
#pragma unroll
            for (int n = 0; n < 4; ++n) {
                int cc = cbase + wn * 64 + n * 16 + l15;
                if (cc < KC) {
                    float bb = bias[cc];
#pragma unroll
                    for (int rr = 0; rr < 4; ++rr) {
                        float lg = acc[m][n][rr] + bb;
                        pe[rr] += __expf(lg);
                        pl[rr] += lg;
                    }
                }
            }
#pragma unroll
            for (int rr = 0; rr < 4; ++rr) {
#pragma unroll
                for (int o = 1; o < 16; o <<= 1) {
                    pe[rr] += __shfl_xor(pe[rr], o);
                    pl[rr] += __shfl_xor(pl[rr], o);
                }
                if (l15 == 0) {
                    int rowl = m * 16 + q * 4 + rr;
                    redE[rowl * 4 + wn] = pe[rr];
                    redL[rowl * 4 + wn] = pl[rr];
                }
            }
        }
        __syncthreads();
        if (tid < 128) {
            float se = redE[tid * 4] + redE[tid * 4 + 1] + redE[tid * 4 + 2] + redE[tid * 4 + 3];
            float sl = redL[tid * 4] + redL[tid * 4 + 1] + redL[tid * 4 + 2] + redL[tid * 4 + 3];
            atomicAdd(&sumexp[rowbase + tid], se);
            atomicAdd(&sumlogit[rowbase + tid], sl);
        }
        __syncthreads();   // LDS free before next task's STAGE(0)
    }
}

// ---------------- final combine ----------------
__global__ __launch_bounds__(1024) void final_kernel(const float* __restrict__ ws,
                                                     float* __restrict__ out) {
    const float* sumexp = ws;
    const float* sumlogit = ws + B;
    const float* t = ws + 2 * B;
    const float* tw = ws + 3 * B;
    int i = threadIdx.x;
    float lse = logf(sumexp[i]);
    float ce = lse - (1.f - EPSSM) * t[i] - (EPSSM / (float)KC) * sumlogit[i];
    float v = ce + tw[i];   // WEIGHT_T = WEIGHT_X = 1
    for (int o = 32; o >= 1; o >>= 1) v += __shfl_xor(v, o);
    __shared__ float red[16];
    int wid = threadIdx.x >> 6, lane = threadIdx.x & 63;
    if (lane == 0) red[wid] = v;
    __syncthreads();
    if (threadIdx.x == 0) {
        float s = 0.f;
#pragma unroll
        for (int w = 0; w < 16; ++w) s += red[w];
        out[0] = s / (float)B;
    }
}

extern "C" void kernel_launch(void* const* d_in, const int* in_sizes, int n_in,
                              void* d_out, int out_size, void* d_ws, size_t ws_size,
                              hipStream_t stream) {
    const float* x = (const float*)d_in[0];
    const float* W = (const float*)d_in[1];
    const float* bias = (const float*)d_in[2];
    const int* labels = (const int*)d_in[3];
    float* out = (float*)d_out;
    float* ws = (float*)d_ws;
    // ws: [0,16KB) stats {sumexp,sumlogit,t,tw}; xp bf16 1MB at +16KB; wp bf16 ~102.5MB.

    unsigned short* xp = (unsigned short*)((char*)d_ws + 16384);
    unsigned short* wp = xp + (size_t)B * D;   // 391 panels * 16 kt * 8192 ushorts

    init_ws<<<(2 * B + 255) / 256, 256, 0, stream>>>(ws);
    pack_w<<<(100096 / 4), 256, 0, stream>>>(W, wp);   // 100096*64/256
    pack_x<<<256, 256, 0, stream>>>(x, xp);
    triplet_kernel<<<B / 8, 256, 0, stream>>>(x, labels, ws + 3 * B);
    tlabel_kernel<<<B / 4, 256, 0, stream>>>(x, W, bias, labels, ws + 2 * B);
    ce_gemm_t<<<512, 256, 49152, stream>>>(xp, wp, bias, ws, ws + B);
    final_kernel<<<1, 1024, 0, stream>>>(ws, out);
}